// Round 6
// baseline (332.613 us; speedup 1.0000x reference)
//
#include <hip/hip_runtime.h>

// out[s, j] = dot(z[s,:], W[c[s]*12288 + j, :]) + b[c[s]*12288 + j]
// z: [1024,128] f32, c: [1024] int, W: [196608,128] f32, b: [196608] f32
// out: [1024, 12288] f32   (12288 = 3*64*64 features per expert)
//
// W-stationary grouped mat-vec. Round-4 post-mortem: VGPR stayed 72 — the
// compiler remats the (invariant, __restrict__) W loads inside the m-loop
// instead of keeping them register-resident. Fix: pin each loaded W component
// as the output of an empty `asm volatile` so it cannot be rematerialized.

#define Z_DIM 128
#define OUT_PER_EXPERT 12288
#define N_EXPERTS 16
#define NT 128
#define MU 4
#define MAX_B 1024

__global__ __launch_bounds__(NT, 3)
void expert_gemm(const float* __restrict__ z,
                 const int* __restrict__ c,
                 const float* __restrict__ W,
                 const float* __restrict__ bias,
                 float* __restrict__ out,
                 int B) {
    const int e = blockIdx.y;

    // --- Build this expert's sample list in LDS ---
    __shared__ int lst[MAX_B];
    __shared__ int cnt_sh;
    if (threadIdx.x == 0) cnt_sh = 0;
    __syncthreads();
    for (int i = threadIdx.x; i < B; i += NT) {
        if (c[i] == e) {
            int p = atomicAdd(&cnt_sh, 1);
            lst[p] = i;
        }
    }
    __syncthreads();
    const int cnt = cnt_sh;
    if (cnt == 0) return;   // expert 15: untouched, no W read

    const int n = blockIdx.x * NT + threadIdx.x;
    const long long row = (long long)e * OUT_PER_EXPERT + n;

    // --- W row stationary in VGPRs; asm pin defeats load-rematerialization ---
    float4 w4[Z_DIM / 4];
    {
        const float4* wp = (const float4*)(W + row * Z_DIM);
        #pragma unroll
        for (int k4 = 0; k4 < Z_DIM / 4; ++k4) {
            w4[k4] = wp[k4];
            asm volatile("" : "+v"(w4[k4].x), "+v"(w4[k4].y),
                              "+v"(w4[k4].z), "+v"(w4[k4].w));
        }
    }
    const float bv = bias[row];

    for (int m0 = 0; m0 < cnt; m0 += MU) {
        const int i1 = min(m0 + 1, cnt - 1);
        const int i2 = min(m0 + 2, cnt - 1);
        const int i3 = min(m0 + 3, cnt - 1);
        // wave-uniform sample ids -> scalar (K$) z loads
        const int s0 = __builtin_amdgcn_readfirstlane(lst[m0]);
        const int s1 = __builtin_amdgcn_readfirstlane(lst[i1]);
        const int s2 = __builtin_amdgcn_readfirstlane(lst[i2]);
        const int s3 = __builtin_amdgcn_readfirstlane(lst[i3]);

        const float4* z0 = (const float4*)(z + (size_t)s0 * Z_DIM);
        const float4* z1 = (const float4*)(z + (size_t)s1 * Z_DIM);
        const float4* z2 = (const float4*)(z + (size_t)s2 * Z_DIM);
        const float4* z3 = (const float4*)(z + (size_t)s3 * Z_DIM);

        float a0 = bv, a1 = bv, a2 = bv, a3 = bv;
        #pragma unroll
        for (int k4 = 0; k4 < Z_DIM / 4; ++k4) {
            const float4 wv = w4[k4];
            const float4 v0 = z0[k4];
            const float4 v1 = z1[k4];
            const float4 v2 = z2[k4];
            const float4 v3 = z3[k4];
            a0 = fmaf(v0.x, wv.x, a0); a0 = fmaf(v0.y, wv.y, a0);
            a0 = fmaf(v0.z, wv.z, a0); a0 = fmaf(v0.w, wv.w, a0);
            a1 = fmaf(v1.x, wv.x, a1); a1 = fmaf(v1.y, wv.y, a1);
            a1 = fmaf(v1.z, wv.z, a1); a1 = fmaf(v1.w, wv.w, a1);
            a2 = fmaf(v2.x, wv.x, a2); a2 = fmaf(v2.y, wv.y, a2);
            a2 = fmaf(v2.z, wv.z, a2); a2 = fmaf(v2.w, wv.w, a2);
            a3 = fmaf(v3.x, wv.x, a3); a3 = fmaf(v3.y, wv.y, a3);
            a3 = fmaf(v3.z, wv.z, a3); a3 = fmaf(v3.w, wv.w, a3);
        }

        out[(size_t)s0 * OUT_PER_EXPERT + n] = a0;
        if (m0 + 1 < cnt) out[(size_t)s1 * OUT_PER_EXPERT + n] = a1;
        if (m0 + 2 < cnt) out[(size_t)s2 * OUT_PER_EXPERT + n] = a2;
        if (m0 + 3 < cnt) out[(size_t)s3 * OUT_PER_EXPERT + n] = a3;
    }
}

extern "C" void kernel_launch(void* const* d_in, const int* in_sizes, int n_in,
                              void* d_out, int out_size, void* d_ws, size_t ws_size,
                              hipStream_t stream) {
    const float* z = (const float*)d_in[0];
    const int*   c = (const int*)d_in[1];
    const float* W = (const float*)d_in[2];
    const float* b = (const float*)d_in[3];
    float* out = (float*)d_out;
    const int B = in_sizes[0] / Z_DIM;   // 1024

    dim3 grid(OUT_PER_EXPERT / NT, N_EXPERTS);
    expert_gemm<<<grid, NT, 0, stream>>>(z, c, W, b, out, B);
}

// Round 7
// 190.253 us; speedup vs baseline: 1.7483x; 1.7483x over previous
//
#include <hip/hip_runtime.h>

// out[s, j] = dot(z[s,:], W[c[s]*12288 + j, :]) + b[c[s]*12288 + j]
// z: [1024,128] f32, c: [1024] int, W: [196608,128] f32, b: [196608] f32
// out: [1024, 12288] f32
//
// Grouped-GEMM via MFMA (16x16x32 bf16), f32 emulated by bf16 hi/lo split:
//   z*W ~= zh*Wh + zh*Wl + zl*Wh   (lo*lo term ~2^-32, dropped)
// Block = (expert, 64 output cols). W tile [64 cols][128 k] converted once
// into LDS (hi/lo); z M-tiles of 16 gathered per iteration. Rows padded to
// 272B so ds_read_b128 fragment reads spread evenly across bank quads.

#define Z_DIM 128
#define OPE   12288       // out feats per expert
#define NEXP  16
#define NT    256         // 4 waves
#define MTILE 16
#define NCOLS 64          // output columns per block
#define WPAD  136         // padded LDS row length in bf16 elems (272 B)

typedef __attribute__((ext_vector_type(8))) short short8;   // 8 bf16 (4 VGPR)
typedef __attribute__((ext_vector_type(4))) float f32x4;
typedef unsigned short u16;
typedef unsigned int   u32;

__device__ __forceinline__ void split_f32(float f, u16& h, u16& l) {
    union { float f; u32 u; } a, b, r;
    a.f = f;
    h = (u16)(a.u >> 16);              // hi = bit-truncated bf16
    b.u = ((u32)h) << 16;
    r.f = f - b.f;                     // exact remainder
    l = (u16)((r.u + 0x8000u) >> 16);  // lo = round-to-nearest bf16
}

__global__ __launch_bounds__(NT, 2)
void expert_mfma(const float* __restrict__ z,
                 const int* __restrict__ c,
                 const float* __restrict__ W,
                 const float* __restrict__ bias,
                 float* __restrict__ out,
                 int B) {
    __shared__ int lst[1024];
    __shared__ int cnt_sh;
    __shared__ __align__(16) u16 Whi[NCOLS][WPAD];   // 17408 B
    __shared__ __align__(16) u16 Wlo[NCOLS][WPAD];   // 17408 B
    __shared__ __align__(16) u16 Zhi[MTILE][WPAD];   //  4352 B
    __shared__ __align__(16) u16 Zlo[MTILE][WPAD];   //  4352 B

    const int tid = threadIdx.x;
    const int e   = blockIdx.y;
    const int n0  = blockIdx.x * NCOLS;

    // --- build expert sample list ---
    if (tid == 0) cnt_sh = 0;
    __syncthreads();
    for (int i = tid; i < B; i += NT)
        if (c[i] == e) lst[atomicAdd(&cnt_sh, 1)] = i;
    __syncthreads();
    const int cnt = cnt_sh;
    if (cnt == 0) return;   // uniform exit (expert 15 unused)

    // --- stage W tile -> bf16 hi/lo LDS, once per block (W HBM-read exactly once) ---
    #pragma unroll
    for (int it = 0; it < 8; ++it) {
        const int chunk = it * NT + tid;      // 2048 float4 chunks = 64 rows x 32
        const int row = chunk >> 5;
        const int kc  = chunk & 31;
        const float4 v = *(const float4*)(W + ((size_t)e * OPE + n0 + row) * Z_DIM + kc * 4);
        u16 h0,h1,h2,h3,l0,l1,l2,l3;
        split_f32(v.x,h0,l0); split_f32(v.y,h1,l1);
        split_f32(v.z,h2,l2); split_f32(v.w,h3,l3);
        uint2 hv, lv;
        hv.x = (u32)h0 | ((u32)h1 << 16); hv.y = (u32)h2 | ((u32)h3 << 16);
        lv.x = (u32)l0 | ((u32)l1 << 16); lv.y = (u32)l2 | ((u32)l3 << 16);
        *(uint2*)&Whi[row][kc * 4] = hv;
        *(uint2*)&Wlo[row][kc * 4] = lv;
    }

    const int lane = tid & 63;
    const int wv   = tid >> 6;        // wave id 0..3 -> cols wv*16..+15
    const int fr   = lane & 15;       // A row / B col within tile
    const int kg   = lane >> 4;       // k-group 0..3 (8 elems each)

    const int   col = n0 + wv * 16 + fr;
    const float bv  = bias[(size_t)e * OPE + col];

    const int zr = tid >> 4;          // z staging row 0..15
    const int zk = (tid & 15) * 8;    // z staging k base

    for (int m0 = 0; m0 < cnt; m0 += MTILE) {
        __syncthreads();  // prior tile's frag reads done; covers W ds_writes on iter 0

        // --- stage z M-tile (gathered rows; zero-pad beyond cnt) ---
        {
            const int r = m0 + zr;
            float4 v0 = {0.f,0.f,0.f,0.f}, v1 = {0.f,0.f,0.f,0.f};
            if (r < cnt) {
                const float* zp = z + (size_t)lst[r] * Z_DIM + zk;
                v0 = *(const float4*)zp;
                v1 = *(const float4*)(zp + 4);
            }
            u16 h[8], l[8];
            split_f32(v0.x,h[0],l[0]); split_f32(v0.y,h[1],l[1]);
            split_f32(v0.z,h[2],l[2]); split_f32(v0.w,h[3],l[3]);
            split_f32(v1.x,h[4],l[4]); split_f32(v1.y,h[5],l[5]);
            split_f32(v1.z,h[6],l[6]); split_f32(v1.w,h[7],l[7]);
            uint4 hv, lv;
            hv.x=(u32)h[0]|((u32)h[1]<<16); hv.y=(u32)h[2]|((u32)h[3]<<16);
            hv.z=(u32)h[4]|((u32)h[5]<<16); hv.w=(u32)h[6]|((u32)h[7]<<16);
            lv.x=(u32)l[0]|((u32)l[1]<<16); lv.y=(u32)l[2]|((u32)l[3]<<16);
            lv.z=(u32)l[4]|((u32)l[5]<<16); lv.w=(u32)l[6]|((u32)l[7]<<16);
            *(uint4*)&Zhi[zr][zk] = hv;
            *(uint4*)&Zlo[zr][zk] = lv;
        }
        __syncthreads();

        // --- 16x16 C tile per wave: 4 k-steps x {hh, hl, lh} ---
        f32x4 acc = {0.f, 0.f, 0.f, 0.f};
        #pragma unroll
        for (int kk = 0; kk < 4; ++kk) {
            const int ko = kk * 32 + kg * 8;
            const short8 ah = *(const short8*)&Zhi[fr][ko];
            const short8 al = *(const short8*)&Zlo[fr][ko];
            const short8 bh = *(const short8*)&Whi[wv * 16 + fr][ko];
            const short8 bl = *(const short8*)&Wlo[wv * 16 + fr][ko];
            acc = __builtin_amdgcn_mfma_f32_16x16x32_bf16(ah, bh, acc, 0, 0, 0);
            acc = __builtin_amdgcn_mfma_f32_16x16x32_bf16(ah, bl, acc, 0, 0, 0);
            acc = __builtin_amdgcn_mfma_f32_16x16x32_bf16(al, bh, acc, 0, 0, 0);
        }

        // --- store: C[row][col], row = kg*4 + j, col = lane&15 (m89/m91 layout) ---
        #pragma unroll
        for (int j = 0; j < 4; ++j) {
            const int r = m0 + kg * 4 + j;
            if (r < cnt)
                out[(size_t)lst[r] * OPE + col] = acc[j] + bv;
        }
    }
}

extern "C" void kernel_launch(void* const* d_in, const int* in_sizes, int n_in,
                              void* d_out, int out_size, void* d_ws, size_t ws_size,
                              hipStream_t stream) {
    const float* z = (const float*)d_in[0];
    const int*   c = (const int*)d_in[1];
    const float* W = (const float*)d_in[2];
    const float* b = (const float*)d_in[3];
    float* out = (float*)d_out;
    const int B = in_sizes[0] / Z_DIM;   // 1024

    dim3 grid(OPE / NCOLS, NEXP);        // 192 x 16
    expert_mfma<<<grid, NT, 0, stream>>>(z, c, W, b, out, B);
}

// Round 9
// 181.053 us; speedup vs baseline: 1.8371x; 1.0508x over previous
//
#include <hip/hip_runtime.h>

// out[s, j] = dot(z[s,:], W[c[s]*12288 + j, :]) + b[c[s]*12288 + j]
// z: [1024,128] f32, c: [1024] int, W: [196608,128] f32, b: [196608] f32
// out: [1024, 12288] f32
//
// Grouped-GEMM via MFMA (16x16x32 bf16), f32 emulated by bf16 hi/lo split:
//   z*W ~= zh*Wh + zh*Wl + zl*Wh
// W fragments live in REGISTERS (32 VGPR/lane, loaded once per block, reused
// for every m-tile — no W LDS). Z staged hi/lo in LDS in 64-row chunks (one
// barrier pair per chunk). Wave = 16 output cols.
// R9 fix: Z-stage q-loop covers all 32 floats/thread (R8 wrote only 16 —
// half of LDS stale -> absmax 1.47).

#define Z_DIM  128
#define OPE    12288
#define NEXP   16
#define NT     256        // 4 waves
#define NCOLS  64         // output cols per block (16 per wave)
#define MCHUNK 64         // z rows staged per barrier pair
#define WPAD   136        // LDS row pitch in bf16 elems (272 B)

typedef __attribute__((ext_vector_type(8))) short short8;   // 8 bf16
typedef __attribute__((ext_vector_type(4))) float f32x4;
typedef unsigned short u16;
typedef unsigned int   u32;

__device__ __forceinline__ void split_f32(float f, u16& h, u16& l) {
    union { float f; u32 u; } a, b, r;
    a.f = f;
    h = (u16)(a.u >> 16);              // hi = truncated bf16
    b.u = ((u32)h) << 16;
    r.f = f - b.f;                     // exact remainder
    l = (u16)((r.u + 0x8000u) >> 16);  // lo = rounded bf16
}

__global__ __launch_bounds__(NT, 4)
void expert_mfma(const float* __restrict__ z,
                 const int* __restrict__ c,
                 const float* __restrict__ W,
                 const float* __restrict__ bias,
                 float* __restrict__ out,
                 int B) {
    __shared__ u16 lst[1024];
    __shared__ int cnt_sh;
    __shared__ __align__(16) u16 Zhi[MCHUNK][WPAD];   // 17408 B
    __shared__ __align__(16) u16 Zlo[MCHUNK][WPAD];   // 17408 B

    const int tid = threadIdx.x;
    const int e   = blockIdx.y;
    const int n0  = blockIdx.x * NCOLS;

    // --- build expert sample list ---
    if (tid == 0) cnt_sh = 0;
    __syncthreads();
    for (int i = tid; i < B; i += NT)
        if (c[i] == e) lst[atomicAdd(&cnt_sh, 1)] = (u16)i;
    __syncthreads();
    const int cnt = cnt_sh;
    if (cnt == 0) return;   // expert 15: unused, uniform exit

    const int lane = tid & 63;
    const int wv   = tid >> 6;        // wave -> col group
    const int fr   = lane & 15;       // tile row/col index
    const int kg   = lane >> 4;       // k-group 0..3

    const int   col = n0 + wv * 16 + fr;
    const float bv  = bias[(size_t)e * OPE + col];

    // --- W B-fragments straight to registers (hi/lo), once per block ---
    short8 bh[4], bl[4];
    {
        const float* wrow = W + ((size_t)e * OPE + col) * Z_DIM;
        #pragma unroll
        for (int kk = 0; kk < 4; ++kk) {
            const float* p = wrow + kk * 32 + kg * 8;
            const float4 v0 = *(const float4*)p;
            const float4 v1 = *(const float4*)(p + 4);
            u16 h[8], l[8];
            split_f32(v0.x,h[0],l[0]); split_f32(v0.y,h[1],l[1]);
            split_f32(v0.z,h[2],l[2]); split_f32(v0.w,h[3],l[3]);
            split_f32(v1.x,h[4],l[4]); split_f32(v1.y,h[5],l[5]);
            split_f32(v1.z,h[6],l[6]); split_f32(v1.w,h[7],l[7]);
            short8 hh, ll;
            hh[0]=(short)h[0]; hh[1]=(short)h[1]; hh[2]=(short)h[2]; hh[3]=(short)h[3];
            hh[4]=(short)h[4]; hh[5]=(short)h[5]; hh[6]=(short)h[6]; hh[7]=(short)h[7];
            ll[0]=(short)l[0]; ll[1]=(short)l[1]; ll[2]=(short)l[2]; ll[3]=(short)l[3];
            ll[4]=(short)l[4]; ll[5]=(short)l[5]; ll[6]=(short)l[6]; ll[7]=(short)l[7];
            bh[kk] = hh; bl[kk] = ll;
        }
    }

    const int zr = tid >> 2;          // staging row 0..63
    const int zq = (tid & 3) * 32;    // staging k base (32 floats per thread)

    for (int m0 = 0; m0 < cnt; m0 += MCHUNK) {
        __syncthreads();   // prior chunk's frag reads complete

        // --- stage 64 gathered z rows -> hi/lo LDS ---
        {
            const int  r     = m0 + zr;
            const bool valid = r < cnt;
            const float* zp  = z + (valid ? (size_t)lst[r] * Z_DIM + zq : 0);
            #pragma unroll
            for (int q = 0; q < 4; ++q) {         // R9 FIX: 4 x 8 floats = all 32
                float4 v0 = {0.f,0.f,0.f,0.f}, v1 = {0.f,0.f,0.f,0.f};
                if (valid) {
                    v0 = *(const float4*)(zp + q * 8);
                    v1 = *(const float4*)(zp + q * 8 + 4);
                }
                u16 h[8], l[8];
                split_f32(v0.x,h[0],l[0]); split_f32(v0.y,h[1],l[1]);
                split_f32(v0.z,h[2],l[2]); split_f32(v0.w,h[3],l[3]);
                split_f32(v1.x,h[4],l[4]); split_f32(v1.y,h[5],l[5]);
                split_f32(v1.z,h[6],l[6]); split_f32(v1.w,h[7],l[7]);
                uint4 hv, lv;
                hv.x=(u32)h[0]|((u32)h[1]<<16); hv.y=(u32)h[2]|((u32)h[3]<<16);
                hv.z=(u32)h[4]|((u32)h[5]<<16); hv.w=(u32)h[6]|((u32)h[7]<<16);
                lv.x=(u32)l[0]|((u32)l[1]<<16); lv.y=(u32)l[2]|((u32)l[3]<<16);
                lv.z=(u32)l[4]|((u32)l[5]<<16); lv.w=(u32)l[6]|((u32)l[7]<<16);
                *(uint4*)&Zhi[zr][zq + q * 8] = hv;
                *(uint4*)&Zlo[zr][zq + q * 8] = lv;
            }
        }
        __syncthreads();

        // --- compute: per 16-row sub-tile, 2 ds_read + 12 MFMA ---
        const int mlim = min(cnt - m0, MCHUNK);
        for (int ms = 0; ms < mlim; ms += 16) {
            f32x4 acc = {0.f, 0.f, 0.f, 0.f};
            #pragma unroll
            for (int kk = 0; kk < 4; ++kk) {
                const int ko = kk * 32 + kg * 8;
                const short8 ah = *(const short8*)&Zhi[ms + fr][ko];
                const short8 al = *(const short8*)&Zlo[ms + fr][ko];
                acc = __builtin_amdgcn_mfma_f32_16x16x32_bf16(ah, bh[kk], acc, 0, 0, 0);
                acc = __builtin_amdgcn_mfma_f32_16x16x32_bf16(ah, bl[kk], acc, 0, 0, 0);
                acc = __builtin_amdgcn_mfma_f32_16x16x32_bf16(al, bh[kk], acc, 0, 0, 0);
            }
            #pragma unroll
            for (int j = 0; j < 4; ++j) {
                const int r = m0 + ms + kg * 4 + j;
                if (r < cnt)
                    out[(size_t)lst[r] * OPE + col] = acc[j] + bv;
            }
        }
    }
}

extern "C" void kernel_launch(void* const* d_in, const int* in_sizes, int n_in,
                              void* d_out, int out_size, void* d_ws, size_t ws_size,
                              hipStream_t stream) {
    const float* z = (const float*)d_in[0];
    const int*   c = (const int*)d_in[1];
    const float* W = (const float*)d_in[2];
    const float* b = (const float*)d_in[3];
    float* out = (float*)d_out;
    const int B = in_sizes[0] / Z_DIM;   // 1024

    dim3 grid(OPE / NCOLS, NEXP);        // 192 x 16
    expert_mfma<<<grid, NT, 0, stream>>>(z, c, W, b, out, B);
}

// Round 12
// 172.163 us; speedup vs baseline: 1.9320x; 1.0516x over previous
//
#include <hip/hip_runtime.h>

// out[s, j] = dot(z[s,:], W[c[s]*12288 + j, :]) + b[c[s]*12288 + j]
// z: [1024,128] f32, c: [1024] int, W: [196608,128] f32, b: [196608] f32
// out: [1024, 12288] f32
//
// Grouped-GEMM via MFMA 16x16x32 bf16, PURE bf16 (RNE) operands, f32 accum.
// Error budget: per-term ~2^-8 rel, 128-term random walk -> ~5e-3 max over
// 12.6M outputs; harness threshold 2.53e-2 (bf16 floor). R9's hi/lo split
// dropped -> 1 MFMA per k-step, half the LDS, half the staging VALU.
// Block = (expert, 128 cols): 4 waves x 2 col-groups. W B-frags in registers
// (16/lane), loaded once per block. Z staged bf16 in LDS, 64-row chunks.
// 1536 blocks x 19.5 KB LDS -> entire grid co-resident (6 blocks/CU).

#define Z_DIM  128
#define OPE    12288
#define NEXP   16
#define NT     256        // 4 waves
#define NCOLS  128        // output cols per block (2 x 16 per wave)
#define MCHUNK 64         // z rows staged per barrier pair
#define WPAD   136        // LDS row pitch in bf16 elems (272 B -> quad rotation)

typedef __attribute__((ext_vector_type(8))) short short8;   // 8 bf16
typedef __attribute__((ext_vector_type(4))) float f32x4;
typedef unsigned short u16;
typedef unsigned int   u32;

__device__ __forceinline__ u16 f2bf(float f) {   // round-to-nearest-even bf16
    union { float f; u32 u; } a; a.f = f;
    const u32 r = a.u + 0x7FFFu + ((a.u >> 16) & 1u);
    return (u16)(r >> 16);
}

__global__ __launch_bounds__(NT, 6)
void expert_mfma(const float* __restrict__ z,
                 const int* __restrict__ c,
                 const float* __restrict__ W,
                 const float* __restrict__ bias,
                 float* __restrict__ out,
                 int B) {
    __shared__ u16 lst[1024];
    __shared__ int cnt_sh;
    __shared__ __align__(16) u16 Zhi[MCHUNK][WPAD];   // 17408 B

    const int tid = threadIdx.x;
    const int e   = blockIdx.y;
    const int n0  = blockIdx.x * NCOLS;

    // --- build expert sample list (c read as one int4 per thread) ---
    if (tid == 0) cnt_sh = 0;
    __syncthreads();
    {
        const int4 cv = ((const int4*)c)[tid];          // 256*4 = 1024
        if (cv.x == e) lst[atomicAdd(&cnt_sh, 1)] = (u16)(tid * 4 + 0);
        if (cv.y == e) lst[atomicAdd(&cnt_sh, 1)] = (u16)(tid * 4 + 1);
        if (cv.z == e) lst[atomicAdd(&cnt_sh, 1)] = (u16)(tid * 4 + 2);
        if (cv.w == e) lst[atomicAdd(&cnt_sh, 1)] = (u16)(tid * 4 + 3);
    }
    __syncthreads();
    const int cnt = cnt_sh;
    if (cnt == 0) return;   // expert 15: unused, uniform exit

    const int lane = tid & 63;
    const int wv   = tid >> 6;        // wave id 0..3
    const int fr   = lane & 15;       // tile row/col index
    const int kg   = lane >> 4;       // k-group 0..3

    const int col0 = n0 + wv * 16 + fr;          // col-group 0
    const int col1 = col0 + 64;                  // col-group 1
    const float bv0 = bias[(size_t)e * OPE + col0];
    const float bv1 = bias[(size_t)e * OPE + col1];

    // --- W B-fragments (bf16) straight to registers, once per block ---
    short8 bh0[4], bh1[4];
    #pragma unroll
    for (int cg = 0; cg < 2; ++cg) {
        const float* wrow = W + ((size_t)e * OPE + (cg ? col1 : col0)) * Z_DIM;
        #pragma unroll
        for (int kk = 0; kk < 4; ++kk) {
            const float* p = wrow + kk * 32 + kg * 8;
            const float4 v0 = *(const float4*)p;
            const float4 v1 = *(const float4*)(p + 4);
            short8 hh;
            hh[0]=(short)f2bf(v0.x); hh[1]=(short)f2bf(v0.y);
            hh[2]=(short)f2bf(v0.z); hh[3]=(short)f2bf(v0.w);
            hh[4]=(short)f2bf(v1.x); hh[5]=(short)f2bf(v1.y);
            hh[6]=(short)f2bf(v1.z); hh[7]=(short)f2bf(v1.w);
            if (cg) bh1[kk] = hh; else bh0[kk] = hh;
        }
    }

    const int zr = tid >> 2;          // staging row 0..63
    const int zq = (tid & 3) * 32;    // staging k base (32 floats per thread)

    for (int m0 = 0; m0 < cnt; m0 += MCHUNK) {
        __syncthreads();   // prior chunk's frag reads (and lst build) complete

        // --- stage valid gathered z rows -> bf16 LDS (invalid rows: stale,
        //     confined to store-masked D rows) ---
        const int r = m0 + zr;
        if (r < cnt) {
            const float* zp = z + (size_t)lst[r] * Z_DIM + zq;
            #pragma unroll
            for (int q = 0; q < 4; ++q) {
                const float4 v0 = *(const float4*)(zp + q * 8);
                const float4 v1 = *(const float4*)(zp + q * 8 + 4);
                uint4 hv;
                hv.x = (u32)f2bf(v0.x) | ((u32)f2bf(v0.y) << 16);
                hv.y = (u32)f2bf(v0.z) | ((u32)f2bf(v0.w) << 16);
                hv.z = (u32)f2bf(v1.x) | ((u32)f2bf(v1.y) << 16);
                hv.w = (u32)f2bf(v1.z) | ((u32)f2bf(v1.w) << 16);
                *(uint4*)&Zhi[zr][zq + q * 8] = hv;
            }
        }
        __syncthreads();

        // --- compute: per 16-row sub-tile, 4 ds_read + 8 MFMA ---
        const int mlim = min(cnt - m0, MCHUNK);
        for (int ms = 0; ms < mlim; ms += 16) {
            f32x4 acc0 = {0.f, 0.f, 0.f, 0.f};
            f32x4 acc1 = {0.f, 0.f, 0.f, 0.f};
            #pragma unroll
            for (int kk = 0; kk < 4; ++kk) {
                const short8 ah = *(const short8*)&Zhi[ms + fr][kk * 32 + kg * 8];
                acc0 = __builtin_amdgcn_mfma_f32_16x16x32_bf16(ah, bh0[kk], acc0, 0, 0, 0);
                acc1 = __builtin_amdgcn_mfma_f32_16x16x32_bf16(ah, bh1[kk], acc1, 0, 0, 0);
            }
            #pragma unroll
            for (int j = 0; j < 4; ++j) {
                const int rr = m0 + ms + kg * 4 + j;
                if (rr < cnt) {
                    float* orow = out + (size_t)lst[rr] * OPE;
                    orow[col0] = acc0[j] + bv0;
                    orow[col1] = acc1[j] + bv1;
                }
            }
        }
    }
}

extern "C" void kernel_launch(void* const* d_in, const int* in_sizes, int n_in,
                              void* d_out, int out_size, void* d_ws, size_t ws_size,
                              hipStream_t stream) {
    const float* z = (const float*)d_in[0];
    const int*   c = (const int*)d_in[1];
    const float* W = (const float*)d_in[2];
    const float* b = (const float*)d_in[3];
    float* out = (float*)d_out;
    const int B = in_sizes[0] / Z_DIM;   // 1024

    dim3 grid(OPE / NCOLS, NEXP);        // 96 x 16 = 1536 blocks, all co-resident
    expert_mfma<<<grid, NT, 0, stream>>>(z, c, W, b, out, B);
}